// Round 1
// baseline (130.810 us; speedup 1.0000x reference)
//
#include <hip/hip_runtime.h>

// SimplifyLoss: Chamfer-style loss.
// preds: [8, 2048, 3] f32   (d_in[0], 49152 elts)
// gts:   [8, 8192, 3] f32   (d_in[1], 196608 elts)
// out:   scalar f32
//
// loss = mean(colmin)          // colmin[b][j] = min_i ||gt_i - pred_j||^2
//      + mean(rowmin)          // rowmin[b][i] = min_j ||gt_i - pred_j||^2
//      + mean_b(max_j colmin[b][j])
//
// ws layout: [0 .. B*N) rowmin bits (uint), [B*N .. B*N+B*M) colmin bits.
// Requires ws_size >= (B*N + B*M)*4 = 327680 bytes.

#define BB 8
#define MM 2048   // preds per batch
#define NN 8192   // gts per batch

__global__ __launch_bounds__(256) void init_k(unsigned* __restrict__ bits,
                                              float* __restrict__ out) {
    int idx = blockIdx.x * 256 + threadIdx.x;
    const int total = BB * NN + BB * MM;
    if (idx < total) bits[idx] = 0x7F800000u;  // +inf
    if (idx == 0) out[0] = 0.0f;
}

// Row mins: for each gt, min over preds. Block = (batch, gt-chunk of 2048, pred-chunk of 256).
// Each thread owns 8 gts (strided), loops over 256 preds staged in LDS.
__global__ __launch_bounds__(256) void row_k(const float* __restrict__ preds,
                                             const float* __restrict__ gts,
                                             unsigned* __restrict__ rowmin) {
    const int b   = blockIdx.x;   // 8
    const int gc  = blockIdx.y;   // 4  (2048 gts each)
    const int pc  = blockIdx.z;   // 8  (256 preds each)
    const int tid = threadIdx.x;

    __shared__ float4 sp[256];
    {
        const float* p = preds + ((size_t)b * MM + pc * 256 + tid) * 3;
        sp[tid] = make_float4(p[0], p[1], p[2], 0.0f);
    }
    __syncthreads();

    float gx[8], gy[8], gz[8], mn[8];
    const int gbase = b * NN + gc * 2048;
#pragma unroll
    for (int k = 0; k < 8; ++k) {
        const float* g = gts + ((size_t)gbase + k * 256 + tid) * 3;
        gx[k] = g[0]; gy[k] = g[1]; gz[k] = g[2];
        mn[k] = 3.4e38f;
    }

    for (int j = 0; j < 256; ++j) {
        float4 q = sp[j];
#pragma unroll
        for (int k = 0; k < 8; ++k) {
            float dx = gx[k] - q.x;
            float dy = gy[k] - q.y;
            float dz = gz[k] - q.z;
            float d  = fmaf(dx, dx, fmaf(dy, dy, dz * dz));
            mn[k] = fminf(mn[k], d);
        }
    }

#pragma unroll
    for (int k = 0; k < 8; ++k)
        atomicMin(&rowmin[gbase + k * 256 + tid], __float_as_uint(mn[k]));
}

// Col mins: for each pred, min over gts. Block = (batch, gt-chunk of 256).
// Each thread owns 8 preds (strided), loops over 256 gts staged in LDS.
__global__ __launch_bounds__(256) void col_k(const float* __restrict__ preds,
                                             const float* __restrict__ gts,
                                             unsigned* __restrict__ colmin) {
    const int b   = blockIdx.x;   // 8
    const int gc  = blockIdx.y;   // 32 (256 gts each)
    const int tid = threadIdx.x;

    __shared__ float4 sg[256];
    {
        const float* g = gts + ((size_t)b * NN + gc * 256 + tid) * 3;
        sg[tid] = make_float4(g[0], g[1], g[2], 0.0f);
    }
    __syncthreads();

    float px[8], py[8], pz[8], mn[8];
#pragma unroll
    for (int k = 0; k < 8; ++k) {
        const float* p = preds + ((size_t)b * MM + k * 256 + tid) * 3;
        px[k] = p[0]; py[k] = p[1]; pz[k] = p[2];
        mn[k] = 3.4e38f;
    }

    for (int i = 0; i < 256; ++i) {
        float4 q = sg[i];
#pragma unroll
        for (int k = 0; k < 8; ++k) {
            float dx = px[k] - q.x;
            float dy = py[k] - q.y;
            float dz = pz[k] - q.z;
            float d  = fmaf(dx, dx, fmaf(dy, dy, dz * dz));
            mn[k] = fminf(mn[k], d);
        }
    }

#pragma unroll
    for (int k = 0; k < 8; ++k)
        atomicMin(&colmin[b * MM + k * 256 + tid], __float_as_uint(mn[k]));
}

__device__ inline float wave_sum(float v) {
#pragma unroll
    for (int o = 32; o > 0; o >>= 1) v += __shfl_down(v, o);
    return v;
}
__device__ inline float wave_max(float v) {
#pragma unroll
    for (int o = 32; o > 0; o >>= 1) v = fmaxf(v, __shfl_down(v, o));
    return v;
}

// One block per batch: reduce rowmin (8192) and colmin (2048) -> sums + max,
// atomicAdd the batch's contribution into the scalar output.
__global__ __launch_bounds__(256) void fin_k(const unsigned* __restrict__ rowmin,
                                             const unsigned* __restrict__ colmin,
                                             float* __restrict__ out) {
    const int b   = blockIdx.x;
    const int tid = threadIdx.x;

    float s_row = 0.0f, s_col = 0.0f, mx = -3.4e38f;
    for (int i = tid; i < NN; i += 256)
        s_row += __uint_as_float(rowmin[b * NN + i]);
    for (int j = tid; j < MM; j += 256) {
        float v = __uint_as_float(colmin[b * MM + j]);
        s_col += v;
        mx = fmaxf(mx, v);
    }

    float wsr = wave_sum(s_row);
    float wsc = wave_sum(s_col);
    float wmx = wave_max(mx);

    __shared__ float ar[4], ac[4], am[4];
    const int wid = tid >> 6, lane = tid & 63;
    if (lane == 0) { ar[wid] = wsr; ac[wid] = wsc; am[wid] = wmx; }
    __syncthreads();

    if (tid == 0) {
        float sr = ar[0] + ar[1] + ar[2] + ar[3];
        float sc = ac[0] + ac[1] + ac[2] + ac[3];
        float mm = fmaxf(fmaxf(am[0], am[1]), fmaxf(am[2], am[3]));
        float contrib = sc / (float)(BB * MM)   // loss_1 (mean of colmin)
                      + sr / (float)(BB * NN)   // loss_2 (mean of rowmin)
                      + mm / (float)BB;         // loss_m (mean of per-batch max)
        atomicAdd(out, contrib);
    }
}

extern "C" void kernel_launch(void* const* d_in, const int* in_sizes, int n_in,
                              void* d_out, int out_size, void* d_ws, size_t ws_size,
                              hipStream_t stream) {
    const float* preds = (const float*)d_in[0];
    const float* gts   = (const float*)d_in[1];
    float* out = (float*)d_out;

    unsigned* rowmin = (unsigned*)d_ws;           // B*N entries
    unsigned* colmin = rowmin + (size_t)BB * NN;  // B*M entries

    const int total = BB * NN + BB * MM;
    init_k<<<(total + 255) / 256, 256, 0, stream>>>(rowmin, out);
    row_k<<<dim3(BB, 4, 8), 256, 0, stream>>>(preds, gts, rowmin);
    col_k<<<dim3(BB, 32), 256, 0, stream>>>(preds, gts, colmin);
    fin_k<<<BB, 256, 0, stream>>>(rowmin, colmin, out);
}

// Round 2
// 101.135 us; speedup vs baseline: 1.2934x; 1.2934x over previous
//
#include <hip/hip_runtime.h>

// SimplifyLoss: Chamfer-style loss, fused single-pass over pairs.
// preds: [8, 2048, 3] f32   (d_in[0])
// gts:   [8, 8192, 3] f32   (d_in[1])
// out:   scalar f32
//
// loss = mean_{b,j}(colmin[b][j])             colmin = min over gts
//      + mean_{b,i}(rowmin[b][i])             rowmin = min over preds
//      + mean_b(max_j colmin[b][j])
//
// K1 pair_k: grid 512 = (b, gtblk of 128 gts), 256 thr = (tx=pred-slot 0..15,
//   ty=gt-group 0..15). Sweeps preds in 16 steps of 128 staged in LDS.
//   Thread computes 8 gts x 8 preds per step. Row-mins complete per block
//   (written unconditionally). Col-mins per step reduced across ty via
//   __shfl_xor (ty = lane bits 0..3) and written as partials [b][gtblk][pred].
// K2 red_k: merges col partials over 64 gtblks -> per-(b,chunk) sum/max
//   partials; also per-batch row sums.
// K3 fin_k: one small block combines 136 floats -> out[0]. No atomics, no
//   init pass anywhere.

#define BB 8
#define MM 2048   // preds per batch
#define NN 8192   // gts per batch

__global__ __launch_bounds__(256) void pair_k(const float* __restrict__ preds,
                                              const float* __restrict__ gts,
                                              float* __restrict__ rowmin,
                                              float* __restrict__ colpart) {
    const int blk   = blockIdx.x;
    const int b     = blk >> 6;
    const int gtblk = blk & 63;
    const int tid   = threadIdx.x;
    const int tx    = tid >> 4;   // pred slot group (0..15) — bits 4.. of lane
    const int ty    = tid & 15;   // gt group (0..15) — lane bits 0..3

    __shared__ float sp[384];        // 128 preds * 3
    __shared__ float red[16 * 128];  // row cross-tx reduce scratch

    // Load my 8 gts (24 contiguous floats, 16B-aligned) via float4.
    float gx[8], gy[8], gz[8];
    {
        const float4* g4 = (const float4*)(gts + ((size_t)(b * NN + gtblk * 128 + ty * 8)) * 3);
        float4 a0 = g4[0], a1 = g4[1], a2 = g4[2], a3 = g4[3], a4 = g4[4], a5 = g4[5];
        gx[0] = a0.x; gy[0] = a0.y; gz[0] = a0.z;
        gx[1] = a0.w; gy[1] = a1.x; gz[1] = a1.y;
        gx[2] = a1.z; gy[2] = a1.w; gz[2] = a2.x;
        gx[3] = a2.y; gy[3] = a2.z; gz[3] = a2.w;
        gx[4] = a3.x; gy[4] = a3.y; gz[4] = a3.z;
        gx[5] = a3.w; gy[5] = a4.x; gz[5] = a4.y;
        gx[6] = a4.z; gy[6] = a4.w; gz[6] = a5.x;
        gx[7] = a5.y; gy[7] = a5.z; gz[7] = a5.w;
    }

    float rmin[8];
#pragma unroll
    for (int i = 0; i < 8; ++i) rmin[i] = 3.4e38f;

    for (int step = 0; step < 16; ++step) {
        __syncthreads();  // protect sp from readers of previous step
        if (tid < 96) {
            const float4* p4 = (const float4*)(preds + ((size_t)(b * MM + step * 128)) * 3);
            ((float4*)sp)[tid] = p4[tid];
        }
        __syncthreads();

        // My 8 preds into registers (LDS reads: 16-lane broadcast per tx,
        // 4 tx per wave at stride 24 floats -> conflict-free).
        float px[8], py[8], pz[8];
#pragma unroll
        for (int j = 0; j < 8; ++j) {
            const int p = (tx * 8 + j) * 3;
            px[j] = sp[p]; py[j] = sp[p + 1]; pz[j] = sp[p + 2];
        }

        float cmin[8];
#pragma unroll
        for (int j = 0; j < 8; ++j) cmin[j] = 3.4e38f;

#pragma unroll
        for (int i = 0; i < 8; ++i) {
#pragma unroll
            for (int j = 0; j < 8; ++j) {
                float dx = gx[i] - px[j];
                float dy = gy[i] - py[j];
                float dz = gz[i] - pz[j];
                float d  = fmaf(dx, dx, fmaf(dy, dy, dz * dz));
                rmin[i]  = fminf(rmin[i], d);
                cmin[j]  = fminf(cmin[j], d);
            }
        }

        // Reduce cmin across ty (lane bits 0..3) -> min over the block's 128 gts.
#pragma unroll
        for (int m = 1; m < 16; m <<= 1) {
#pragma unroll
            for (int j = 0; j < 8; ++j)
                cmin[j] = fminf(cmin[j], __shfl_xor(cmin[j], m, 64));
        }
        if (ty == 0) {
            float4* dst = (float4*)&colpart[(((size_t)b * 64 + gtblk) * MM) + step * 128 + tx * 8];
            dst[0] = make_float4(cmin[0], cmin[1], cmin[2], cmin[3]);
            dst[1] = make_float4(cmin[4], cmin[5], cmin[6], cmin[7]);
        }
    }

    // Row-min cross-tx reduce (once): rmin[i] covers only this tx's pred slots.
    __syncthreads();
#pragma unroll
    for (int i = 0; i < 8; ++i) red[tx * 128 + ty * 8 + i] = rmin[i];
    __syncthreads();
    if (tid < 128) {
        float m = red[tid];
#pragma unroll
        for (int k = 1; k < 16; ++k) m = fminf(m, red[k * 128 + tid]);
        rowmin[(size_t)b * NN + gtblk * 128 + tid] = m;
    }
}

// K2: y<8 -> col chunk (256 preds): colmin over 64 gtblks, then block sum+max.
//     y==8 -> per-batch row sum.
__global__ __launch_bounds__(256) void red_k(const float* __restrict__ rowmin,
                                             const float* __restrict__ colpart,
                                             float* __restrict__ colsum_p,
                                             float* __restrict__ colmax_p,
                                             float* __restrict__ rowsum_p) {
    const int b = blockIdx.x, y = blockIdx.y, tid = threadIdx.x;
    __shared__ float a1[4], a2[4];

    if (y < 8) {
        const int p = y * 256 + tid;
        const float* cp = colpart + (size_t)b * 64 * MM + p;
        float m = 3.4e38f;
#pragma unroll 8
        for (int g = 0; g < 64; ++g) m = fminf(m, cp[(size_t)g * MM]);
        float s = m, mx = m;
#pragma unroll
        for (int o = 32; o > 0; o >>= 1) {
            s += __shfl_down(s, o, 64);
            mx = fmaxf(mx, __shfl_down(mx, o, 64));
        }
        const int w = tid >> 6, lane = tid & 63;
        if (lane == 0) { a1[w] = s; a2[w] = mx; }
        __syncthreads();
        if (tid == 0) {
            colsum_p[b * 8 + y] = a1[0] + a1[1] + a1[2] + a1[3];
            colmax_p[b * 8 + y] = fmaxf(fmaxf(a2[0], a2[1]), fmaxf(a2[2], a2[3]));
        }
    } else {
        float s = 0.0f;
        for (int i = tid; i < NN; i += 256) s += rowmin[(size_t)b * NN + i];
#pragma unroll
        for (int o = 32; o > 0; o >>= 1) s += __shfl_down(s, o, 64);
        const int w = tid >> 6, lane = tid & 63;
        if (lane == 0) a1[w] = s;
        __syncthreads();
        if (tid == 0) rowsum_p[b] = a1[0] + a1[1] + a1[2] + a1[3];
    }
}

__global__ __launch_bounds__(64) void fin_k(const float* __restrict__ colsum_p,
                                            const float* __restrict__ colmax_p,
                                            const float* __restrict__ rowsum_p,
                                            float* __restrict__ out) {
    __shared__ float s_cs[64], s_cm[64], s_rs[8];
    const int t = threadIdx.x;
    s_cs[t] = colsum_p[t];
    s_cm[t] = colmax_p[t];
    if (t < 8) s_rs[t] = rowsum_p[t];
    __syncthreads();
    if (t == 0) {
        float cs = 0.0f, rs = 0.0f, mm = 0.0f;
        for (int i = 0; i < 64; ++i) cs += s_cs[i];
        for (int b = 0; b < 8; ++b) {
            float mx = s_cm[b * 8];
            for (int c = 1; c < 8; ++c) mx = fmaxf(mx, s_cm[b * 8 + c]);
            mm += mx;
            rs += s_rs[b];
        }
        out[0] = cs / (float)(BB * MM)   // loss_1: mean of colmin
               + rs / (float)(BB * NN)   // loss_2: mean of rowmin
               + mm / (float)BB;         // loss_m: mean of per-batch max
    }
}

extern "C" void kernel_launch(void* const* d_in, const int* in_sizes, int n_in,
                              void* d_out, int out_size, void* d_ws, size_t ws_size,
                              hipStream_t stream) {
    const float* preds = (const float*)d_in[0];
    const float* gts   = (const float*)d_in[1];
    float* out = (float*)d_out;

    // ws layout (floats): rowmin[BB*NN] | colpart[BB*64*MM] | colsum_p[64] |
    //                     colmax_p[64] | rowsum_p[8]   (~4.3 MB total)
    float* rowmin   = (float*)d_ws;
    float* colpart  = rowmin + (size_t)BB * NN;
    float* colsum_p = colpart + (size_t)BB * 64 * MM;
    float* colmax_p = colsum_p + 64;
    float* rowsum_p = colmax_p + 64;

    pair_k<<<512, 256, 0, stream>>>(preds, gts, rowmin, colpart);
    red_k<<<dim3(BB, 9), 256, 0, stream>>>(rowmin, colpart, colsum_p, colmax_p, rowsum_p);
    fin_k<<<1, 64, 0, stream>>>(colsum_p, colmax_p, rowsum_p, out);
}